// Round 1
// baseline (374.829 us; speedup 1.0000x reference)
//
#include <hip/hip_runtime.h>
#include <stdint.h>

typedef short bf16x8 __attribute__((ext_vector_type(8)));
typedef float f32x4 __attribute__((ext_vector_type(4)));

#define MFMA_BF16(a, b, c) __builtin_amdgcn_mfma_f32_16x16x32_bf16((a), (b), (c), 0, 0, 0)

__device__ __forceinline__ unsigned short f2bf(float x) {
  union { float f; unsigned int u; } v; v.f = x;
  unsigned int r = (v.u + 0x7FFFu + ((v.u >> 16) & 1u)) >> 16;
  return (unsigned short)r;
}

// ---------------------------------------------------------------- convert
__global__ void __launch_bounds__(256) cvt_f32_bf16(const float* __restrict__ in,
                                                    unsigned short* __restrict__ out,
                                                    int n4) {
  int i = blockIdx.x * blockDim.x + threadIdx.x;
  int stride = gridDim.x * blockDim.x;
  for (; i < n4; i += stride) {
    float4 v = ((const float4*)in)[i];
    ushort4 o;
    o.x = f2bf(v.x); o.y = f2bf(v.y); o.z = f2bf(v.z); o.w = f2bf(v.w);
    ((ushort4*)out)[i] = o;
  }
}

// ---------------------------------------------------------------- GEMM
// C[m,n] = sum_k A[m,k] * B[n,k]  (A: [M,1024] bf16, B: [N,1024] bf16 row-major)
// MODE 0: Q epilogue  -> bf16 [B,H,T,D], (acc+bias)*0.125
// MODE 1: K epilogue  -> bf16 [B,H,T,D], acc+bias
// MODE 2: V epilogue  -> bf16 [B,H,D,T] (transposed), acc+bias
// MODE 3: proj        -> f32  [M,1024], acc+bias
template <int MODE>
__global__ void __launch_bounds__(256) gemm_bt(const unsigned short* __restrict__ A,
                                               const unsigned short* __restrict__ Bw,
                                               const float* __restrict__ bias,
                                               void* __restrict__ out) {
  constexpr int K = 1024;
  __shared__ unsigned short As[128 * 32];
  __shared__ unsigned short Bs[128 * 32];

  const int tid = threadIdx.x;
  const int wid = tid >> 6;
  const int l = tid & 63;
  const int g = l >> 4;
  const int ln = l & 15;

  const int m0 = blockIdx.y * 128;
  const int n0 = blockIdx.x * 128;
  const int wm = (wid >> 1) * 64;
  const int wn = (wid & 1) * 64;

  f32x4 acc[4][4];
  for (int i = 0; i < 4; ++i)
    for (int j = 0; j < 4; ++j) acc[i][j] = (f32x4){0.f, 0.f, 0.f, 0.f};

  // staging geometry: 8 segments of 1024B per tile; wave w owns segments {2w, 2w+1}
  const int s0 = wid * 2;
  const int rowBase = s0 * 16 + (l >> 2);  // row within 128-row tile
  const int cb = (l & 3) * 8;              // ushort offset within 32-wide k slice

  for (int kt = 0; kt < K; kt += 32) {
    __syncthreads();  // previous iter's LDS reads done
#pragma unroll
    for (int i = 0; i < 2; ++i) {
      int row = rowBase + i * 16;
      const unsigned short* ga = A + (size_t)(m0 + row) * K + kt + cb;
      const unsigned short* gb = Bw + (size_t)(n0 + row) * K + kt + cb;
      __builtin_amdgcn_global_load_lds((const __attribute__((address_space(1))) void*)ga,
                                       (__attribute__((address_space(3))) void*)&As[(s0 + i) * 512],
                                       16, 0, 0);
      __builtin_amdgcn_global_load_lds((const __attribute__((address_space(1))) void*)gb,
                                       (__attribute__((address_space(3))) void*)&Bs[(s0 + i) * 512],
                                       16, 0, 0);
    }
    __syncthreads();  // drains vmcnt(0): staged data visible

    bf16x8 af[4], bfr[4];
#pragma unroll
    for (int mi = 0; mi < 4; ++mi) af[mi] = *(const bf16x8*)&As[(wm + mi * 16 + ln) * 32 + g * 8];
#pragma unroll
    for (int ni = 0; ni < 4; ++ni) bfr[ni] = *(const bf16x8*)&Bs[(wn + ni * 16 + ln) * 32 + g * 8];
#pragma unroll
    for (int mi = 0; mi < 4; ++mi)
#pragma unroll
      for (int ni = 0; ni < 4; ++ni) acc[mi][ni] = MFMA_BF16(af[mi], bfr[ni], acc[mi][ni]);
  }

  // epilogue. D layout: row = (l>>4)*4 + r, col = l&15
  const int mBase = m0 + wm + g * 4;
  const int nBase = n0 + wn + ln;

  if (MODE == 3) {
    float* O = (float*)out;
#pragma unroll
    for (int mi = 0; mi < 4; ++mi) {
      int m = mBase + mi * 16;
#pragma unroll
      for (int ni = 0; ni < 4; ++ni) {
        int n = nBase + ni * 16;
        float bv = bias[n];
#pragma unroll
        for (int r = 0; r < 4; ++r) O[(size_t)(m + r) * 1024 + n] = acc[mi][ni][r] + bv;
      }
    }
  } else {
    unsigned short* O = (unsigned short*)out;
#pragma unroll
    for (int mi = 0; mi < 4; ++mi) {
      int m = mBase + mi * 16;
      int b = m >> 11, t = m & 2047;
#pragma unroll
      for (int ni = 0; ni < 4; ++ni) {
        int n = nBase + ni * 16;
        int h = n >> 6, d = n & 63;
        float bv = bias[n];
        if (MODE == 2) {
          ushort4 pk;
          pk.x = f2bf(acc[mi][ni][0] + bv);
          pk.y = f2bf(acc[mi][ni][1] + bv);
          pk.z = f2bf(acc[mi][ni][2] + bv);
          pk.w = f2bf(acc[mi][ni][3] + bv);
          *(ushort4*)&O[((size_t)((b * 16 + h) * 64 + d)) * 2048 + t] = pk;
        } else {
          const float sc = (MODE == 0) ? 0.125f : 1.0f;
#pragma unroll
          for (int r = 0; r < 4; ++r)
            O[((size_t)(b * 16 + h) * 2048 + (t + r)) * 64 + d] = f2bf((acc[mi][ni][r] + bv) * sc);
        }
      }
    }
  }
}

// ---------------------------------------------------------------- attention
// Q,K: [BH=64][T=2048][D=64] bf16 (Q pre-scaled by 1/8). Vt: [64][64][2048] bf16.
// Y out: [B,T,C] bf16. 4 independent waves per block, 32 q-rows per wave, KBLK=64.
__global__ void __launch_bounds__(256) attn_kernel(const unsigned short* __restrict__ Q,
                                                   const unsigned short* __restrict__ K,
                                                   const unsigned short* __restrict__ Vt,
                                                   unsigned short* __restrict__ Y) {
  __shared__ unsigned short P[4][32 * 72];  // per-wave P tile, stride 72 keeps 16B align
  const int tid = threadIdx.x;
  const int wid = tid >> 6;
  const int l = tid & 63;
  const int g = l >> 4, ln = l & 15;
  const int bh = blockIdx.y;
  const int q0 = blockIdx.x * 128 + wid * 32;

  const unsigned short* Qp = Q + (size_t)bh * 2048 * 64;
  const unsigned short* Kp = K + (size_t)bh * 2048 * 64;
  const unsigned short* Vp = Vt + (size_t)bh * 64 * 2048;

  bf16x8 aq[2][2];
#pragma unroll
  for (int mi = 0; mi < 2; ++mi)
#pragma unroll
    for (int kk = 0; kk < 2; ++kk)
      aq[mi][kk] = *(const bf16x8*)&Qp[(size_t)(q0 + mi * 16 + ln) * 64 + kk * 32 + g * 8];

  f32x4 o[2][4];
  float mst[2][4], lst[2][4];
#pragma unroll
  for (int mi = 0; mi < 2; ++mi) {
#pragma unroll
    for (int di = 0; di < 4; ++di) o[mi][di] = (f32x4){0.f, 0.f, 0.f, 0.f};
#pragma unroll
    for (int r = 0; r < 4; ++r) { mst[mi][r] = -1e30f; lst[mi][r] = 0.f; }
  }

  unsigned short* Pl = &P[wid][0];

  for (int k0 = 0; k0 < q0 + 32; k0 += 64) {
    f32x4 s[2][4];
#pragma unroll
    for (int mi = 0; mi < 2; ++mi)
#pragma unroll
      for (int ni = 0; ni < 4; ++ni) s[mi][ni] = (f32x4){0.f, 0.f, 0.f, 0.f};

#pragma unroll
    for (int ni = 0; ni < 4; ++ni) {
      bf16x8 kb0 = *(const bf16x8*)&Kp[(size_t)(k0 + ni * 16 + ln) * 64 + g * 8];
      bf16x8 kb1 = *(const bf16x8*)&Kp[(size_t)(k0 + ni * 16 + ln) * 64 + 32 + g * 8];
#pragma unroll
      for (int mi = 0; mi < 2; ++mi) {
        s[mi][ni] = MFMA_BF16(aq[mi][0], kb0, s[mi][ni]);
        s[mi][ni] = MFMA_BF16(aq[mi][1], kb1, s[mi][ni]);
      }
    }

    if (k0 + 63 > q0) {  // diagonal region: apply causal mask
#pragma unroll
      for (int mi = 0; mi < 2; ++mi)
#pragma unroll
        for (int ni = 0; ni < 4; ++ni) {
          int kg = k0 + ni * 16 + ln;
#pragma unroll
          for (int r = 0; r < 4; ++r) {
            int qg = q0 + mi * 16 + g * 4 + r;
            if (kg > qg) s[mi][ni][r] = -1e30f;
          }
        }
    }

#pragma unroll
    for (int mi = 0; mi < 2; ++mi) {
      float pm[4], sf[4];
#pragma unroll
      for (int r = 0; r < 4; ++r) {
        float v = fmaxf(fmaxf(s[mi][0][r], s[mi][1][r]), fmaxf(s[mi][2][r], s[mi][3][r]));
#pragma unroll
        for (int off = 1; off < 16; off <<= 1) v = fmaxf(v, __shfl_xor(v, off));
        pm[r] = v;
      }
#pragma unroll
      for (int r = 0; r < 4; ++r) {
        float mn = fmaxf(mst[mi][r], pm[r]);
        sf[r] = __expf(mst[mi][r] - mn);
        mst[mi][r] = mn;
      }
      float rs[4] = {0.f, 0.f, 0.f, 0.f};
#pragma unroll
      for (int ni = 0; ni < 4; ++ni)
#pragma unroll
        for (int r = 0; r < 4; ++r) {
          float p = __expf(s[mi][ni][r] - mst[mi][r]);
          s[mi][ni][r] = p;
          rs[r] += p;
        }
#pragma unroll
      for (int r = 0; r < 4; ++r) {
        float v = rs[r];
#pragma unroll
        for (int off = 1; off < 16; off <<= 1) v += __shfl_xor(v, off);
        lst[mi][r] = lst[mi][r] * sf[r] + v;
      }
#pragma unroll
      for (int di = 0; di < 4; ++di)
#pragma unroll
        for (int r = 0; r < 4; ++r) o[mi][di][r] *= sf[r];
#pragma unroll
      for (int ni = 0; ni < 4; ++ni)
#pragma unroll
        for (int r = 0; r < 4; ++r)
          Pl[(mi * 16 + g * 4 + r) * 72 + ni * 16 + ln] = f2bf(s[mi][ni][r]);
    }

    // PV: O += P * V   (A-frag from LDS, B-frag = Vt rows, contiguous in k)
#pragma unroll
    for (int ks = 0; ks < 2; ++ks) {
      bf16x8 pa[2];
#pragma unroll
      for (int mi = 0; mi < 2; ++mi)
        pa[mi] = *(const bf16x8*)&Pl[(mi * 16 + ln) * 72 + ks * 32 + g * 8];
#pragma unroll
      for (int di = 0; di < 4; ++di) {
        bf16x8 vb = *(const bf16x8*)&Vp[(size_t)(di * 16 + ln) * 2048 + k0 + ks * 32 + g * 8];
#pragma unroll
        for (int mi = 0; mi < 2; ++mi) o[mi][di] = MFMA_BF16(pa[mi], vb, o[mi][di]);
      }
    }
  }

  const int b = bh >> 4, h = bh & 15;
#pragma unroll
  for (int mi = 0; mi < 2; ++mi)
#pragma unroll
    for (int di = 0; di < 4; ++di)
#pragma unroll
      for (int r = 0; r < 4; ++r) {
        int qg = q0 + mi * 16 + g * 4 + r;
        float val = o[mi][di][r] / lst[mi][r];
        Y[(size_t)(b * 2048 + qg) * 1024 + h * 64 + di * 16 + ln] = f2bf(val);
      }
}

// ---------------------------------------------------------------- launch
extern "C" void kernel_launch(void* const* d_in, const int* in_sizes, int n_in,
                              void* d_out, int out_size, void* d_ws, size_t ws_size,
                              hipStream_t stream) {
  const float* x = (const float*)d_in[0];
  const float* Wk = (const float*)d_in[1];
  const float* bk = (const float*)d_in[2];
  const float* Wq = (const float*)d_in[3];
  const float* bq = (const float*)d_in[4];
  const float* Wv = (const float*)d_in[5];
  const float* bv = (const float*)d_in[6];
  const float* Wp = (const float*)d_in[7];
  const float* bp = (const float*)d_in[8];
  float* out = (float*)d_out;

  // workspace layout (bytes)
  char* ws = (char*)d_ws;
  unsigned short* xb  = (unsigned short*)(ws);                 // 16 MiB
  unsigned short* wkb = (unsigned short*)(ws + 16777216);      // 2 MiB
  unsigned short* wqb = (unsigned short*)(ws + 18874368);      // 2 MiB
  unsigned short* wvb = (unsigned short*)(ws + 20971520);      // 2 MiB
  unsigned short* wpb = (unsigned short*)(ws + 23068672);      // 2 MiB
  unsigned short* Qb  = (unsigned short*)(ws + 25165824);      // 16 MiB [B,H,T,D]
  unsigned short* Kb  = (unsigned short*)(ws + 41943040);      // 16 MiB [B,H,T,D]
  unsigned short* Vtb = (unsigned short*)(ws + 58720256);      // 16 MiB [B,H,D,T]
  unsigned short* yb  = (unsigned short*)(ws + 75497472);      // 16 MiB [M,1024]
  if (ws_size < 92274688u) return;

  cvt_f32_bf16<<<dim3(2048), dim3(256), 0, stream>>>(x, xb, 8388608 / 4);
  cvt_f32_bf16<<<dim3(1024), dim3(256), 0, stream>>>(Wk, wkb, 1048576 / 4);
  cvt_f32_bf16<<<dim3(1024), dim3(256), 0, stream>>>(Wq, wqb, 1048576 / 4);
  cvt_f32_bf16<<<dim3(1024), dim3(256), 0, stream>>>(Wv, wvb, 1048576 / 4);
  cvt_f32_bf16<<<dim3(1024), dim3(256), 0, stream>>>(Wp, wpb, 1048576 / 4);

  dim3 gg(8, 64);  // N/128, M/128
  gemm_bt<1><<<gg, dim3(256), 0, stream>>>(xb, wkb, bk, (void*)Kb);
  gemm_bt<0><<<gg, dim3(256), 0, stream>>>(xb, wqb, bq, (void*)Qb);
  gemm_bt<2><<<gg, dim3(256), 0, stream>>>(xb, wvb, bv, (void*)Vtb);

  attn_kernel<<<dim3(16, 64), dim3(256), 0, stream>>>(Qb, Kb, Vtb, yb);

  gemm_bt<3><<<gg, dim3(256), 0, stream>>>(yb, wpb, bp, (void*)out);
}

// Round 2
// 204.694 us; speedup vs baseline: 1.8312x; 1.8312x over previous
//
#include <hip/hip_runtime.h>
#include <stdint.h>

typedef short bf16x8 __attribute__((ext_vector_type(8)));
typedef float f32x4 __attribute__((ext_vector_type(4)));
typedef float f32x16 __attribute__((ext_vector_type(16)));

#define MFMA16(a, b, c) __builtin_amdgcn_mfma_f32_16x16x32_bf16((a), (b), (c), 0, 0, 0)
#define MFMA32(a, b, c) __builtin_amdgcn_mfma_f32_32x32x16_bf16((a), (b), (c), 0, 0, 0)

__device__ __forceinline__ unsigned short f2bf(float x) {
  union { float f; unsigned int u; } v; v.f = x;
  unsigned int r = (v.u + 0x7FFFu + ((v.u >> 16) & 1u)) >> 16;
  return (unsigned short)r;
}

__device__ __forceinline__ unsigned int cvtpk(float lo, float hi) {
  unsigned int r;
  asm("v_cvt_pk_bf16_f32 %0, %1, %2" : "=v"(r) : "v"(lo), "v"(hi));
  return r;
}

// v_permlane32_swap_b32 a, b: a[hi lanes] <- b_old[lo lanes], b[lo lanes] <- a_old[hi lanes]
__device__ __forceinline__ void plswap(unsigned int& a, unsigned int& b) {
  asm("v_permlane32_swap_b32 %0, %1" : "+v"(a), "+v"(b));
}

// ---------------------------------------------------------------- convert
__global__ void __launch_bounds__(256) cvt_f32_bf16(const float* __restrict__ in,
                                                    unsigned short* __restrict__ out,
                                                    int n4) {
  int i = blockIdx.x * blockDim.x + threadIdx.x;
  int stride = gridDim.x * blockDim.x;
  for (; i < n4; i += stride) {
    float4 v = ((const float4*)in)[i];
    ushort4 o;
    o.x = f2bf(v.x); o.y = f2bf(v.y); o.z = f2bf(v.z); o.w = f2bf(v.w);
    ((ushort4*)out)[i] = o;
  }
}

// ---------------------------------------------------------------- GEMM (unchanged from R1)
template <int MODE>
__global__ void __launch_bounds__(256) gemm_bt(const unsigned short* __restrict__ A,
                                               const unsigned short* __restrict__ Bw,
                                               const float* __restrict__ bias,
                                               void* __restrict__ out) {
  constexpr int K = 1024;
  __shared__ unsigned short As[128 * 32];
  __shared__ unsigned short Bs[128 * 32];

  const int tid = threadIdx.x;
  const int wid = tid >> 6;
  const int l = tid & 63;
  const int g = l >> 4;
  const int ln = l & 15;

  const int m0 = blockIdx.y * 128;
  const int n0 = blockIdx.x * 128;
  const int wm = (wid >> 1) * 64;
  const int wn = (wid & 1) * 64;

  f32x4 acc[4][4];
  for (int i = 0; i < 4; ++i)
    for (int j = 0; j < 4; ++j) acc[i][j] = (f32x4){0.f, 0.f, 0.f, 0.f};

  const int s0 = wid * 2;
  const int rowBase = s0 * 16 + (l >> 2);
  const int cb = (l & 3) * 8;

  for (int kt = 0; kt < K; kt += 32) {
    __syncthreads();
#pragma unroll
    for (int i = 0; i < 2; ++i) {
      int row = rowBase + i * 16;
      const unsigned short* ga = A + (size_t)(m0 + row) * K + kt + cb;
      const unsigned short* gb = Bw + (size_t)(n0 + row) * K + kt + cb;
      __builtin_amdgcn_global_load_lds((const __attribute__((address_space(1))) void*)ga,
                                       (__attribute__((address_space(3))) void*)&As[(s0 + i) * 512],
                                       16, 0, 0);
      __builtin_amdgcn_global_load_lds((const __attribute__((address_space(1))) void*)gb,
                                       (__attribute__((address_space(3))) void*)&Bs[(s0 + i) * 512],
                                       16, 0, 0);
    }
    __syncthreads();

    bf16x8 af[4], bfr[4];
#pragma unroll
    for (int mi = 0; mi < 4; ++mi) af[mi] = *(const bf16x8*)&As[(wm + mi * 16 + ln) * 32 + g * 8];
#pragma unroll
    for (int ni = 0; ni < 4; ++ni) bfr[ni] = *(const bf16x8*)&Bs[(wn + ni * 16 + ln) * 32 + g * 8];
#pragma unroll
    for (int mi = 0; mi < 4; ++mi)
#pragma unroll
      for (int ni = 0; ni < 4; ++ni) acc[mi][ni] = MFMA16(af[mi], bfr[ni], acc[mi][ni]);
  }

  const int mBase = m0 + wm + g * 4;
  const int nBase = n0 + wn + ln;

  if (MODE == 3) {
    float* O = (float*)out;
#pragma unroll
    for (int mi = 0; mi < 4; ++mi) {
      int m = mBase + mi * 16;
#pragma unroll
      for (int ni = 0; ni < 4; ++ni) {
        int n = nBase + ni * 16;
        float bv = bias[n];
#pragma unroll
        for (int r = 0; r < 4; ++r) O[(size_t)(m + r) * 1024 + n] = acc[mi][ni][r] + bv;
      }
    }
  } else {
    unsigned short* O = (unsigned short*)out;
#pragma unroll
    for (int mi = 0; mi < 4; ++mi) {
      int m = mBase + mi * 16;
      int b = m >> 11, t = m & 2047;
#pragma unroll
      for (int ni = 0; ni < 4; ++ni) {
        int n = nBase + ni * 16;
        int h = n >> 6, d = n & 63;
        float bv = bias[n];
        if (MODE == 2) {
          ushort4 pk;
          pk.x = f2bf(acc[mi][ni][0] + bv);
          pk.y = f2bf(acc[mi][ni][1] + bv);
          pk.z = f2bf(acc[mi][ni][2] + bv);
          pk.w = f2bf(acc[mi][ni][3] + bv);
          *(ushort4*)&O[((size_t)((b * 16 + h) * 64 + d)) * 2048 + t] = pk;
        } else {
          const float sc = (MODE == 0) ? 0.125f : 1.0f;
#pragma unroll
          for (int r = 0; r < 4; ++r)
            O[((size_t)(b * 16 + h) * 2048 + (t + r)) * 64 + d] = f2bf((acc[mi][ni][r] + bv) * sc);
        }
      }
    }
  }
}

// ---------------------------------------------------------------- attention (swapped-QK^T, in-register softmax)
// Q,K: [BH=64][T=2048][D=64] bf16 (Q pre-scaled by 1/8). Vt: [64][64][2048] bf16.
// Block: 4 waves x 32 q-rows = 128 q. KV tile = 64, double-buffered LDS, XOR-swizzled.
__global__ void __launch_bounds__(256) attn_kernel(const unsigned short* __restrict__ Q,
                                                   const unsigned short* __restrict__ K,
                                                   const unsigned short* __restrict__ Vt,
                                                   unsigned short* __restrict__ Y) {
  __shared__ unsigned short Ks[2][64 * 64];
  __shared__ unsigned short Vs[2][64 * 64];

  const int tid = threadIdx.x;
  const int wid = tid >> 6;
  const int l = tid & 63;
  const int q32 = l & 31;
  const int hi = l >> 5;
  const int bh = blockIdx.x;
  const int qblk = 15 - blockIdx.y;      // heavy blocks dispatch first
  const int q0b = qblk * 128;
  const int q0w = q0b + wid * 32;

  const unsigned short* Qp = Q + (size_t)bh * 2048 * 64;
  const unsigned short* Kp = K + (size_t)bh * 2048 * 64;
  const unsigned short* Vp = Vt + (size_t)bh * 64 * 2048;

  // Q fragments (B-operand): q = q0w+q32, d = kk*16 + hi*8 + 0..7
  bf16x8 qf[4];
#pragma unroll
  for (int kk = 0; kk < 4; ++kk)
    qf[kk] = *(const bf16x8*)&Qp[(size_t)(q0w + q32) * 64 + kk * 16 + hi * 8];

  f32x16 o0, o1;
#pragma unroll
  for (int r = 0; r < 16; ++r) { o0[r] = 0.f; o1[r] = 0.f; }
  float m = -1e30f, lst = 0.f;

  // staging: thread tid covers chunk (ri*256+tid); row = chunk>>3, c = chunk&7, src chunk c^(row&7)
  const int srow = tid >> 3;
  const int sc = tid & 7;

  const int nt = qblk * 2 + 2;                  // block max tiles
  const int myNt = (q0w + 32 + 63) >> 6;        // this wave's tiles

#define STAGE(bufi, kk0)                                                                          \
  {                                                                                               \
    _Pragma("unroll") for (int ri = 0; ri < 2; ++ri) {                                            \
      int row = ri * 32 + srow;                                                                   \
      int csw = sc ^ (row & 7);                                                                   \
      const unsigned short* gk = Kp + (size_t)(kk0 + row) * 64 + csw * 8;                         \
      const unsigned short* gv = Vp + (size_t)row * 2048 + (kk0) + csw * 8;                       \
      __builtin_amdgcn_global_load_lds((const __attribute__((address_space(1))) void*)gk,         \
                                       (__attribute__((address_space(3))) void*)                  \
                                           &Ks[bufi][(ri * 256 + wid * 64) * 8],                  \
                                       16, 0, 0);                                                 \
      __builtin_amdgcn_global_load_lds((const __attribute__((address_space(1))) void*)gv,         \
                                       (__attribute__((address_space(3))) void*)                  \
                                           &Vs[bufi][(ri * 256 + wid * 64) * 8],                  \
                                       16, 0, 0);                                                 \
    }                                                                                             \
  }

  int buf = 0;
  STAGE(0, 0);
  __syncthreads();

  for (int t = 0; t < nt; ++t) {
    const int k0 = t * 64;
    if (t + 1 < nt) STAGE(buf ^ 1, k0 + 64);

    if (t < myNt) {
      // ---- QK^T (swapped): S^T[k, q], A = K rows, B = Q rows
      f32x16 s0, s1;
#pragma unroll
      for (int r = 0; r < 16; ++r) { s0[r] = 0.f; s1[r] = 0.f; }
      const int xr = q32 & 7;
#pragma unroll
      for (int kk = 0; kk < 4; ++kk) {
        bf16x8 kf0 = *(const bf16x8*)&Ks[buf][q32 * 64 + (((kk << 1) | hi) ^ xr) * 8];
        bf16x8 kf1 = *(const bf16x8*)&Ks[buf][(32 + q32) * 64 + (((kk << 1) | hi) ^ xr) * 8];
        s0 = MFMA32(kf0, qf[kk], s0);
        s1 = MFMA32(kf1, qf[kk], s1);
      }

      // ---- causal mask (diagonal tiles only)
      if (k0 + 63 > q0w) {
        const int qg = q0w + q32;
#pragma unroll
        for (int r = 0; r < 16; ++r) {
          int kr = (r & 3) + 8 * (r >> 2) + 4 * hi;
          if (k0 + kr > qg) s0[r] = -1e30f;
          if (k0 + 32 + kr > qg) s1[r] = -1e30f;
        }
      }

      // ---- online softmax (per-lane row = its q column), defer-max THR=8
      float pm = s0[0];
#pragma unroll
      for (int r = 1; r < 16; ++r) pm = fmaxf(pm, s0[r]);
#pragma unroll
      for (int r = 0; r < 16; ++r) pm = fmaxf(pm, s1[r]);
      pm = fmaxf(pm, __shfl_xor(pm, 32));

      if (__any(pm > m + 8.0f)) {
        float mn = fmaxf(m, pm);
        float sf = __expf(m - mn);
        m = mn;
        lst *= sf;
#pragma unroll
        for (int r = 0; r < 16; ++r) {
          float sb = __shfl(sf, (r & 3) + 8 * (r >> 2) + 4 * hi);
          o0[r] *= sb;
          o1[r] *= sb;
        }
      }
      float rs = 0.f;
#pragma unroll
      for (int r = 0; r < 16; ++r) { s0[r] = __expf(s0[r] - m); rs += s0[r]; }
#pragma unroll
      for (int r = 0; r < 16; ++r) { s1[r] = __expf(s1[r] - m); rs += s1[r]; }
      rs += __shfl_xor(rs, 32);
      lst += rs;

      // ---- P -> bf16 A-frags: 16 cvt_pk + 8 permlane32_swap
      union { unsigned int u[4]; bf16x8 v; } pa[4];
#pragma unroll
      for (int t2 = 0; t2 < 2; ++t2) {
        const f32x16& sv = t2 ? s1 : s0;
#pragma unroll
        for (int sl = 0; sl < 2; ++sl) {
          int base = sl * 8;
          unsigned int x0 = cvtpk(sv[base + 0], sv[base + 1]);
          unsigned int x1 = cvtpk(sv[base + 2], sv[base + 3]);
          unsigned int x2 = cvtpk(sv[base + 4], sv[base + 5]);
          unsigned int x3 = cvtpk(sv[base + 6], sv[base + 7]);
          plswap(x0, x2);
          plswap(x1, x3);
          int ksg = t2 * 2 + sl;
          pa[ksg].u[0] = x0; pa[ksg].u[1] = x1; pa[ksg].u[2] = x2; pa[ksg].u[3] = x3;
        }
      }

      // ---- PV: O[q,d] += P[q,k] * V[k,d]; B = Vt rows from LDS
#pragma unroll
      for (int ksg = 0; ksg < 4; ++ksg) {
        bf16x8 v0 = *(const bf16x8*)&Vs[buf][q32 * 64 + (((ksg << 1) | hi) ^ xr) * 8];
        bf16x8 v1 = *(const bf16x8*)&Vs[buf][(32 + q32) * 64 + (((ksg << 1) | hi) ^ xr) * 8];
        o0 = MFMA32(pa[ksg].v, v0, o0);
        o1 = MFMA32(pa[ksg].v, v1, o1);
      }
    }

    __syncthreads();  // drains stage vmcnt + orders buffer reuse
    buf ^= 1;
  }

  // ---- epilogue: divide by l (gather to O layout), store bf16
  const int b = bh >> 4, h = bh & 15;
#pragma unroll
  for (int r = 0; r < 16; ++r) {
    int qsrc = (r & 3) + 8 * (r >> 2) + 4 * hi;
    int qg = q0w + qsrc;
    float lq = __shfl(lst, qsrc);
    float inv = 1.0f / lq;
    size_t rowb = (size_t)(b * 2048 + qg) * 1024 + h * 64;
    Y[rowb + q32] = f2bf(o0[r] * inv);
    Y[rowb + 32 + q32] = f2bf(o1[r] * inv);
  }
#undef STAGE
}

// ---------------------------------------------------------------- launch
extern "C" void kernel_launch(void* const* d_in, const int* in_sizes, int n_in,
                              void* d_out, int out_size, void* d_ws, size_t ws_size,
                              hipStream_t stream) {
  const float* x = (const float*)d_in[0];
  const float* Wk = (const float*)d_in[1];
  const float* bk = (const float*)d_in[2];
  const float* Wq = (const float*)d_in[3];
  const float* bq = (const float*)d_in[4];
  const float* Wv = (const float*)d_in[5];
  const float* bv = (const float*)d_in[6];
  const float* Wp = (const float*)d_in[7];
  const float* bp = (const float*)d_in[8];
  float* out = (float*)d_out;

  char* ws = (char*)d_ws;
  unsigned short* xb  = (unsigned short*)(ws);
  unsigned short* wkb = (unsigned short*)(ws + 16777216);
  unsigned short* wqb = (unsigned short*)(ws + 18874368);
  unsigned short* wvb = (unsigned short*)(ws + 20971520);
  unsigned short* wpb = (unsigned short*)(ws + 23068672);
  unsigned short* Qb  = (unsigned short*)(ws + 25165824);
  unsigned short* Kb  = (unsigned short*)(ws + 41943040);
  unsigned short* Vtb = (unsigned short*)(ws + 58720256);
  unsigned short* yb  = (unsigned short*)(ws + 75497472);
  if (ws_size < 92274688u) return;

  cvt_f32_bf16<<<dim3(2048), dim3(256), 0, stream>>>(x, xb, 8388608 / 4);
  cvt_f32_bf16<<<dim3(1024), dim3(256), 0, stream>>>(Wk, wkb, 1048576 / 4);
  cvt_f32_bf16<<<dim3(1024), dim3(256), 0, stream>>>(Wq, wqb, 1048576 / 4);
  cvt_f32_bf16<<<dim3(1024), dim3(256), 0, stream>>>(Wv, wvb, 1048576 / 4);
  cvt_f32_bf16<<<dim3(1024), dim3(256), 0, stream>>>(Wp, wpb, 1048576 / 4);

  dim3 gg(8, 64);
  gemm_bt<1><<<gg, dim3(256), 0, stream>>>(xb, wkb, bk, (void*)Kb);
  gemm_bt<0><<<gg, dim3(256), 0, stream>>>(xb, wqb, bq, (void*)Qb);
  gemm_bt<2><<<gg, dim3(256), 0, stream>>>(xb, wvb, bv, (void*)Vtb);

  attn_kernel<<<dim3(64, 16), dim3(256), 0, stream>>>(Qb, Kb, Vtb, yb);

  gemm_bt<3><<<gg, dim3(256), 0, stream>>>(yb, wpb, bp, (void*)out);
}